// Round 8
// baseline (323.135 us; speedup 1.0000x reference)
//
#include <hip/hip_runtime.h>
#include <hip/hip_bf16.h>
#include <math.h>

typedef short short8 __attribute__((ext_vector_type(8)));
typedef float f32x4 __attribute__((ext_vector_type(4)));

static __device__ __forceinline__ float bfu(unsigned short u) {
    union { unsigned int i; float f; } c; c.i = ((unsigned int)u) << 16; return c.f;
}
static __device__ __forceinline__ ushort f2bu(float f) {
    __hip_bfloat16 h = __float2bfloat16(f);
    return *(ushort*)&h;
}

// ---------------- prep: Wt[n][k] = bf16(W[k][n]), coalesced via LDS tile ----------------

__global__ __launch_bounds__(256) void k_wt_cast3(const float* __restrict__ W1, const float* __restrict__ W2,
                           const float* __restrict__ W3, __hip_bfloat16* __restrict__ Wt1,
                           __hip_bfloat16* __restrict__ Wt2, __hip_bfloat16* __restrict__ Wt3) {
    __shared__ float t[64][65];
    const float* W = (blockIdx.z == 0) ? W1 : (blockIdx.z == 1) ? W2 : W3;
    __hip_bfloat16* Wt = (blockIdx.z == 0) ? Wt1 : (blockIdx.z == 1) ? Wt2 : Wt3;
    int k0 = blockIdx.x * 64, n0 = blockIdx.y * 64;
#pragma unroll
    for (int i = 0; i < 16; ++i) {
        int idx = threadIdx.x + 256 * i;
        int r = idx >> 6, c = idx & 63;
        t[r][c] = W[(size_t)(k0 + r) * 256 + n0 + c];   // coalesced rows of W
    }
    __syncthreads();
#pragma unroll
    for (int i = 0; i < 16; ++i) {
        int idx = threadIdx.x + 256 * i;
        int r = idx >> 6, c = idx & 63;
        Wt[(size_t)(n0 + r) * 256 + k0 + c] = __float2bfloat16(t[c][r]);  // coalesced rows of Wt
    }
}

// ---------------- CSR build ----------------

__global__ void k_set1(int* a, int n) {
    int i = blockIdx.x * blockDim.x + threadIdx.x;
    if (i < n) a[i] = 1; // self-loop
}

__global__ void k_hist(const int* __restrict__ dstv, int* __restrict__ cnt, int E) {
    int i = blockIdx.x * blockDim.x + threadIdx.x;
    if (i < E) atomicAdd(&cnt[dstv[i]], 1);
}

__global__ void k_scan1(const int* __restrict__ cnt, int* __restrict__ excl, int* __restrict__ bsum, int n) {
    __shared__ int s[256];
    int i = blockIdx.x * 256 + threadIdx.x;
    int v = (i < n) ? cnt[i] : 0;
    s[threadIdx.x] = v;
    __syncthreads();
    for (int off = 1; off < 256; off <<= 1) {
        int t = (threadIdx.x >= off) ? s[threadIdx.x - off] : 0;
        __syncthreads();
        s[threadIdx.x] += t;
        __syncthreads();
    }
    if (i < n) excl[i] = s[threadIdx.x] - v;
    if (threadIdx.x == 255) bsum[blockIdx.x] = s[255];
}

__global__ void k_scan2(const int* __restrict__ bsum, int* __restrict__ boff, int nb) {
    __shared__ int s[256];
    int carry = 0;
    for (int base = 0; base < nb; base += 256) {
        int i = base + threadIdx.x;
        int v = (i < nb) ? bsum[i] : 0;
        s[threadIdx.x] = v;
        __syncthreads();
        for (int off = 1; off < 256; off <<= 1) {
            int t = (threadIdx.x >= off) ? s[threadIdx.x - off] : 0;
            __syncthreads();
            s[threadIdx.x] += t;
            __syncthreads();
        }
        if (i < nb) boff[i] = carry + s[threadIdx.x] - v;
        carry += s[255];
        __syncthreads();
    }
}

__global__ void k_scan3(const int* __restrict__ excl, const int* __restrict__ boff,
                        int* __restrict__ rowptr, int* __restrict__ cursor, int n, int Etot) {
    int i = blockIdx.x * blockDim.x + threadIdx.x;
    if (i < n) {
        int v = excl[i] + boff[i >> 8];
        rowptr[i] = v;
        cursor[i] = v;
    }
    if (i == 0) rowptr[n] = Etot;
}

__global__ void k_scatter(const int* __restrict__ srcv, const int* __restrict__ dstv,
                          int* __restrict__ cursor, int* __restrict__ colsrc, int E, int Nn) {
    int i = blockIdx.x * blockDim.x + threadIdx.x;
    if (i < E) {
        int pos = atomicAdd(&cursor[dstv[i]], 1);
        colsrc[pos] = srcv[i];
    } else if (i < E + Nn) {
        int nn = i - E;
        int pos = atomicAdd(&cursor[nn], 1);
        colsrc[pos] = nn;
    }
}

// ---------------- GEMM + fused attention scores ----------------
// C[M][256] = A[M][256] @ W  (Wt is [n][k] bf16).
// K=256, N=256 tiny => B entirely in VGPRs (wave w preloads head w's
// 64x256 panel = 32 x dwordx4, L2-hot); A staged ONCE full-K (32KB LDS,
// swizzled), ONE barrier, 8 k-steps x 16 MFMA straight through.
// K-offset per (kk,hi): a lane's 8 bf16 sit at k = kk*32 + hi*8
//   => BYTE offset kk*64 + hi*16.  (R6 bug: kk*128+hi*32 -> OOB LDS -> fault)
// AFP32: layer-1 reads fp32 x directly, converting during staging.

template <bool AFP32>
__global__ __launch_bounds__(256, 2) void k_gemm(const void* __restrict__ Ap,
                                              const __hip_bfloat16* __restrict__ Wt,
                                              __hip_bfloat16* __restrict__ C,
                                              const float* __restrict__ a_src,
                                              const float* __restrict__ a_dst,
                                              float* __restrict__ es,
                                              float* __restrict__ ed, int M) {
    __shared__ __align__(16) char As[64 * 512];   // 64 rows x 256 bf16 (full K, swizzled)
    int tid = threadIdx.x;
    int w = tid >> 6, l = tid & 63;
    int lo = l & 15, hi = l >> 4;
    int m0 = blockIdx.x * 64;

    // B-panel resident in VGPRs: row (w*64+ni*16+lo), bytes [kk*64+hi*16, +16)
    short8 bfr[4][8];
#pragma unroll
    for (int ni = 0; ni < 4; ++ni)
#pragma unroll
        for (int kk = 0; kk < 8; ++kk)
            bfr[ni][kk] = *(const short8*)((const char*)Wt +
                (size_t)(w * 64 + ni * 16 + lo) * 512 + kk * 64 + hi * 16);

    // stage A (full K) swizzled into LDS
#pragma unroll
    for (int i = 0; i < 8; ++i) {
        int c = tid + 256 * i;
        int row = c >> 5, ko = c & 31;
        int rg = m0 + row;
        uint4 v = {0u, 0u, 0u, 0u};
        if (rg < M) {
            if (AFP32) {
                const float* Af = (const float*)Ap;
                float4 f0 = *(const float4*)(Af + (size_t)rg * 256 + ko * 8);
                float4 f1 = *(const float4*)(Af + (size_t)rg * 256 + ko * 8 + 4);
                v.x = (uint)f2bu(f0.x) | ((uint)f2bu(f0.y) << 16);
                v.y = (uint)f2bu(f0.z) | ((uint)f2bu(f0.w) << 16);
                v.z = (uint)f2bu(f1.x) | ((uint)f2bu(f1.y) << 16);
                v.w = (uint)f2bu(f1.z) | ((uint)f2bu(f1.w) << 16);
            } else {
                v = *(const uint4*)((const char*)Ap + (size_t)rg * 512 + ko * 16);
            }
        }
        *(uint4*)(As + row * 512 + ((ko * 16) ^ ((row & 7) << 4))) = v;
    }
    __syncthreads();

    f32x4 acc[4][4];
#pragma unroll
    for (int a = 0; a < 4; ++a)
#pragma unroll
        for (int b = 0; b < 4; ++b) acc[a][b] = (f32x4){0.f, 0.f, 0.f, 0.f};

#pragma unroll
    for (int kk = 0; kk < 8; ++kk) {
#pragma unroll
        for (int mi = 0; mi < 4; ++mi) {
            int row = mi * 16 + lo;
            short8 af = *(const short8*)(As + row * 512 +
                        ((kk * 64 + hi * 16) ^ ((row & 7) << 4)));
#pragma unroll
            for (int ni = 0; ni < 4; ++ni)
                acc[mi][ni] = __builtin_amdgcn_mfma_f32_16x16x32_bf16(af, bfr[ni][kk], acc[mi][ni], 0, 0, 0);
        }
    }

    // C write
#pragma unroll
    for (int mi = 0; mi < 4; ++mi) {
#pragma unroll
        for (int r = 0; r < 4; ++r) {
            int rg = m0 + mi * 16 + hi * 4 + r;
            if (rg < M) {
#pragma unroll
                for (int ni = 0; ni < 4; ++ni) {
                    int col = w * 64 + ni * 16 + lo;
                    C[(size_t)rg * 256 + col] = __float2bfloat16(acc[mi][ni][r]);
                }
            }
        }
    }
    // fused e_src/e_dst (head w lives entirely in wave w)
    float avv[4], adv[4];
#pragma unroll
    for (int ni = 0; ni < 4; ++ni) {
        avv[ni] = a_src[w * 64 + ni * 16 + lo];
        adv[ni] = a_dst[w * 64 + ni * 16 + lo];
    }
#pragma unroll
    for (int mi = 0; mi < 4; ++mi) {
#pragma unroll
        for (int r = 0; r < 4; ++r) {
            int rg = m0 + mi * 16 + hi * 4 + r;
            float s1 = 0.f, s2 = 0.f;
#pragma unroll
            for (int ni = 0; ni < 4; ++ni) {
                s1 += acc[mi][ni][r] * avv[ni];
                s2 += acc[mi][ni][r] * adv[ni];
            }
#pragma unroll
            for (int mk = 1; mk < 16; mk <<= 1) {
                s1 += __shfl_xor(s1, mk, 64);
                s2 += __shfl_xor(s2, mk, 64);
            }
            if (lo == 0 && rg < M) {
                es[rg * 4 + w] = s1;
                ed[rg * 4 + w] = s2;
            }
        }
    }
}

// ---------------- softmax + aggregate ----------------
// One WAVE per dst node; lane l owns channels [4l..4l+3] (head = l>>4).
// Register-only masked 8-deep unroll (measured local roofline: ~56us at
// ~4 TB/s random-512B L2-fill; FETCH ~167MB is compulsory per-XCD traffic).
// No max subtraction: e = leaky_relu(es+ed) is O(+-10); fp32 exp safe.
// mode 0: out = bf16(relu(acc+b) + x);  1: bf16(relu(acc+b));  2: fp32 relu(acc+b+x)

__global__ __launch_bounds__(256) void k_aggregate(const __hip_bfloat16* __restrict__ hW,
                            const int* __restrict__ rowptr,
                            const int* __restrict__ colsrc, const float* __restrict__ es,
                            const float* __restrict__ edv_, const float* __restrict__ bias,
                            const float* __restrict__ xres, __hip_bfloat16* __restrict__ outbf,
                            float* __restrict__ outf, int mode, int Nn) {
    int n = blockIdx.x * 4 + (threadIdx.x >> 6);
    if (n >= Nn) return;
    int l = threadIdx.x & 63;
    int h = l >> 4;
    int r0 = rowptr[n];
    int deg = rowptr[n + 1] - r0;
    float edv = edv_[n * 4 + h];

    float denom = 0.f;
    float a0 = 0.f, a1 = 0.f, a2 = 0.f, a3 = 0.f;
    const ushort* hw = (const ushort*)hW;
    int sfb = colsrc[r0];  // fallback row for masked lanes (self-loop => deg>=1)

    for (int base = 0; base < deg; base += 8) {
        int sv[8];
#pragma unroll
        for (int u = 0; u < 8; ++u)
            sv[u] = (base + u < deg) ? colsrc[r0 + base + u] : sfb;
        float ev[8];
#pragma unroll
        for (int u = 0; u < 8; ++u)
            ev[u] = es[(size_t)sv[u] * 4 + h];
        uint2 hv[8];
#pragma unroll
        for (int u = 0; u < 8; ++u)
            hv[u] = *(const uint2*)(hw + (size_t)sv[u] * 256 + l * 4);
#pragma unroll
        for (int u = 0; u < 8; ++u) {
            float t = ev[u] + edv;
            t = fmaxf(t, 0.2f * t);
            float p = (base + u < deg) ? __expf(t) : 0.f;
            denom += p;
            a0 += p * bfu((ushort)(hv[u].x & 0xffff));
            a1 += p * bfu((ushort)(hv[u].x >> 16));
            a2 += p * bfu((ushort)(hv[u].y & 0xffff));
            a3 += p * bfu((ushort)(hv[u].y >> 16));
        }
    }

    float inv = 1.f / (denom + 1e-16f);
    int idx = n * 256 + l * 4;
    float4 b4 = *(const float4*)(bias + l * 4);
    float v0 = a0 * inv + b4.x;
    float v1 = a1 * inv + b4.y;
    float v2 = a2 * inv + b4.z;
    float v3 = a3 * inv + b4.w;

    if (mode == 2) {
        float4 x4 = *(const float4*)(xres + idx);
        float4 o;
        o.x = fmaxf(v0 + x4.x, 0.f);
        o.y = fmaxf(v1 + x4.y, 0.f);
        o.z = fmaxf(v2 + x4.z, 0.f);
        o.w = fmaxf(v3 + x4.w, 0.f);
        *(float4*)(outf + idx) = o;
    } else {
        v0 = fmaxf(v0, 0.f); v1 = fmaxf(v1, 0.f);
        v2 = fmaxf(v2, 0.f); v3 = fmaxf(v3, 0.f);
        if (mode == 0) {
            float4 x4 = *(const float4*)(xres + idx);
            v0 += x4.x; v1 += x4.y; v2 += x4.z; v3 += x4.w;
        }
        union { ushort u[4]; uint2 v; } o;
        o.u[0] = f2bu(v0); o.u[1] = f2bu(v1);
        o.u[2] = f2bu(v2); o.u[3] = f2bu(v3);
        *(uint2*)((ushort*)outbf + idx) = o.v;
    }
}

// ---------------- launch ----------------

extern "C" void kernel_launch(void* const* d_in, const int* in_sizes, int n_in,
                              void* d_out, int out_size, void* d_ws, size_t ws_size,
                              hipStream_t stream) {
    const float* x  = (const float*)d_in[0];
    const int* ei   = (const int*)d_in[1];
    const float* W1 = (const float*)d_in[2];
    const float* as1 = (const float*)d_in[3];
    const float* ad1 = (const float*)d_in[4];
    const float* b1  = (const float*)d_in[5];
    const float* W2  = (const float*)d_in[6];
    const float* as2 = (const float*)d_in[7];
    const float* ad2 = (const float*)d_in[8];
    const float* b2  = (const float*)d_in[9];
    const float* WN  = (const float*)d_in[10];
    const float* asN = (const float*)d_in[11];
    const float* adN = (const float*)d_in[12];
    const float* bN  = (const float*)d_in[13];

    int Nn = in_sizes[0] / 256;
    int E = in_sizes[1] / 2;
    const int* srcv = ei;
    const int* dstv = ei + E;
    int Etot = E + Nn;

    char* p = (char*)d_ws;
    auto alloc = [&](size_t bytes) {
        char* r = p;
        p += (bytes + 255) & ~(size_t)255;
        return r;
    };
    __hip_bfloat16* Pbf  = (__hip_bfloat16*)alloc((size_t)Nn * 256 * 2);
    __hip_bfloat16* Qbf  = (__hip_bfloat16*)alloc((size_t)Nn * 256 * 2);
    __hip_bfloat16* hWbf = (__hip_bfloat16*)alloc((size_t)Nn * 256 * 2);
    __hip_bfloat16* Wt1  = (__hip_bfloat16*)alloc(256 * 256 * 2);
    __hip_bfloat16* Wt2  = (__hip_bfloat16*)alloc(256 * 256 * 2);
    __hip_bfloat16* Wt3  = (__hip_bfloat16*)alloc(256 * 256 * 2);
    float* esrc = (float*)alloc((size_t)Nn * 4 * 4);
    float* edst = (float*)alloc((size_t)Nn * 4 * 4);
    int* cnt    = (int*)alloc((size_t)Nn * 4);
    int* excl   = (int*)alloc((size_t)Nn * 4);
    int* rowptr = (int*)alloc((size_t)(Nn + 1) * 4);
    int* cursor = (int*)alloc((size_t)Nn * 4);
    int* bsum   = (int*)alloc(4096);
    int* boff   = (int*)alloc(4096);
    int* colsrc = (int*)alloc((size_t)Etot * 4);

    int nb = (Nn + 255) / 256;

    // prep: weight transpose+cast (coalesced, one launch)
    dim3 wg(4, 4, 3);
    k_wt_cast3<<<wg, 256, 0, stream>>>(W1, W2, WN, Wt1, Wt2, Wt3);

    // CSR build (dst-sorted, with self-loops)
    k_set1<<<nb, 256, 0, stream>>>(cnt, Nn);
    k_hist<<<(E + 255) / 256, 256, 0, stream>>>(dstv, cnt, E);
    k_scan1<<<nb, 256, 0, stream>>>(cnt, excl, bsum, Nn);
    k_scan2<<<1, 256, 0, stream>>>(bsum, boff, nb);
    k_scan3<<<nb, 256, 0, stream>>>(excl, boff, rowptr, cursor, Nn, Etot);
    k_scatter<<<(Etot + 255) / 256, 256, 0, stream>>>(srcv, dstv, cursor, colsrc, E, Nn);

    int gg = (Nn + 63) / 64;
    int ga = (Nn + 3) / 4;

    // layer 1 (fp32 x staged directly)
    k_gemm<true><<<gg, 256, 0, stream>>>(x, Wt1, hWbf, as1, ad1, esrc, edst, Nn);
    k_aggregate<<<ga, 256, 0, stream>>>(hWbf, rowptr, colsrc, esrc, edst, b1, x, Pbf, nullptr, 0, Nn);
    // layer 2
    k_gemm<false><<<gg, 256, 0, stream>>>(Pbf, Wt2, hWbf, as2, ad2, esrc, edst, Nn);
    k_aggregate<<<ga, 256, 0, stream>>>(hWbf, rowptr, colsrc, esrc, edst, b2, x, Qbf, nullptr, 1, Nn);
    // layer 3
    k_gemm<false><<<gg, 256, 0, stream>>>(Qbf, Wt3, hWbf, asN, adN, esrc, edst, Nn);
    k_aggregate<<<ga, 256, 0, stream>>>(hWbf, rowptr, colsrc, esrc, edst, bN, x, nullptr, (float*)d_out, 2, Nn);
}

// Round 9
// 295.502 us; speedup vs baseline: 1.0935x; 1.0935x over previous
//
#include <hip/hip_runtime.h>
#include <hip/hip_bf16.h>
#include <math.h>

typedef short short8 __attribute__((ext_vector_type(8)));
typedef float f32x4 __attribute__((ext_vector_type(4)));

static __device__ __forceinline__ float bfu(unsigned short u) {
    union { unsigned int i; float f; } c; c.i = ((unsigned int)u) << 16; return c.f;
}
static __device__ __forceinline__ ushort f2bu(float f) {
    __hip_bfloat16 h = __float2bfloat16(f);
    return *(ushort*)&h;
}
// async global->LDS, 16B per lane; LDS dest is wave-uniform base + lane*16
static __device__ __forceinline__ void gload_lds16(const void* g, void* l) {
    __builtin_amdgcn_global_load_lds(
        (const __attribute__((address_space(1))) void*)g,
        (__attribute__((address_space(3))) void*)l, 16, 0, 0);
}

// ---------------- prep: Wt[n][k] = bf16(W[k][n]), coalesced via LDS tile ----------------

__global__ __launch_bounds__(256) void k_wt_cast3(const float* __restrict__ W1, const float* __restrict__ W2,
                           const float* __restrict__ W3, __hip_bfloat16* __restrict__ Wt1,
                           __hip_bfloat16* __restrict__ Wt2, __hip_bfloat16* __restrict__ Wt3) {
    __shared__ float t[64][65];
    const float* W = (blockIdx.z == 0) ? W1 : (blockIdx.z == 1) ? W2 : W3;
    __hip_bfloat16* Wt = (blockIdx.z == 0) ? Wt1 : (blockIdx.z == 1) ? Wt2 : Wt3;
    int k0 = blockIdx.x * 64, n0 = blockIdx.y * 64;
#pragma unroll
    for (int i = 0; i < 16; ++i) {
        int idx = threadIdx.x + 256 * i;
        int r = idx >> 6, c = idx & 63;
        t[r][c] = W[(size_t)(k0 + r) * 256 + n0 + c];   // coalesced rows of W
    }
    __syncthreads();
#pragma unroll
    for (int i = 0; i < 16; ++i) {
        int idx = threadIdx.x + 256 * i;
        int r = idx >> 6, c = idx & 63;
        Wt[(size_t)(n0 + r) * 256 + k0 + c] = __float2bfloat16(t[c][r]);  // coalesced rows of Wt
    }
}

// ---------------- CSR build ----------------

// cnt must be zeroed beforehand (hipMemsetAsync). Self-loops folded in here.
__global__ void k_hist(const int* __restrict__ dstv, int* __restrict__ cnt, int E, int Nn) {
    int i = blockIdx.x * blockDim.x + threadIdx.x;
    if (i < E) atomicAdd(&cnt[dstv[i]], 1);
    else if (i < E + Nn) atomicAdd(&cnt[i - E], 1);
}

__global__ void k_scan1(const int* __restrict__ cnt, int* __restrict__ excl, int* __restrict__ bsum, int n) {
    __shared__ int s[256];
    int i = blockIdx.x * 256 + threadIdx.x;
    int v = (i < n) ? cnt[i] : 0;
    s[threadIdx.x] = v;
    __syncthreads();
    for (int off = 1; off < 256; off <<= 1) {
        int t = (threadIdx.x >= off) ? s[threadIdx.x - off] : 0;
        __syncthreads();
        s[threadIdx.x] += t;
        __syncthreads();
    }
    if (i < n) excl[i] = s[threadIdx.x] - v;
    if (threadIdx.x == 255) bsum[blockIdx.x] = s[255];
}

__global__ void k_scan2(const int* __restrict__ bsum, int* __restrict__ boff, int nb) {
    __shared__ int s[256];
    int carry = 0;
    for (int base = 0; base < nb; base += 256) {
        int i = base + threadIdx.x;
        int v = (i < nb) ? bsum[i] : 0;
        s[threadIdx.x] = v;
        __syncthreads();
        for (int off = 1; off < 256; off <<= 1) {
            int t = (threadIdx.x >= off) ? s[threadIdx.x - off] : 0;
            __syncthreads();
            s[threadIdx.x] += t;
            __syncthreads();
        }
        if (i < nb) boff[i] = carry + s[threadIdx.x] - v;
        carry += s[255];
        __syncthreads();
    }
}

__global__ void k_scan3(const int* __restrict__ excl, const int* __restrict__ boff,
                        int* __restrict__ rowptr, int* __restrict__ cursor, int n, int Etot) {
    int i = blockIdx.x * blockDim.x + threadIdx.x;
    if (i < n) {
        int v = excl[i] + boff[i >> 8];
        rowptr[i] = v;
        cursor[i] = v;
    }
    if (i == 0) rowptr[n] = Etot;
}

__global__ void k_scatter(const int* __restrict__ srcv, const int* __restrict__ dstv,
                          int* __restrict__ cursor, int* __restrict__ colsrc, int E, int Nn) {
    int i = blockIdx.x * blockDim.x + threadIdx.x;
    if (i < E) {
        int pos = atomicAdd(&cursor[dstv[i]], 1);
        colsrc[pos] = srcv[i];
    } else if (i < E + Nn) {
        int nn = i - E;
        int pos = atomicAdd(&cursor[nn], 1);
        colsrc[pos] = nn;
    }
}

// ---------------- GEMM + fused attention scores ----------------
// C[M][256] = A[M][256] @ W  (Wt is [n][k] bf16). R5 proven shape (BM=64,
// BK=64, 4 iters, 2 barriers/iter) but staged via global_load_lds width=16:
// LDS dest is LINEAR (offset c*16), the XOR swizzle is applied to the
// GLOBAL source address; the LDS read applies the same XOR -> involution
// composes to identity (guide m173 / rule #21).
// AFP32 (layer 1): A staged via masked VGPR+convert path (can't gload_lds
// a dtype conversion); B still gload_lds.
// bf16 A layers: rows >= M read garbage inside padded ws buffers (masked at
// C/es write) -- Pbf/Qbf are padded by one full tile.

template <bool AFP32>
__global__ __launch_bounds__(256) void k_gemm(const void* __restrict__ Ap,
                                              const __hip_bfloat16* __restrict__ Wt,
                                              __hip_bfloat16* __restrict__ C,
                                              const float* __restrict__ a_src,
                                              const float* __restrict__ a_dst,
                                              float* __restrict__ es,
                                              float* __restrict__ ed, int M) {
    __shared__ __align__(16) char As[64 * 128];   // 64 rows x 64 bf16 (swizzled)
    __shared__ __align__(16) char Bs[256 * 128];  // 256 n-rows x 64 bf16 (swizzled)
    int tid = threadIdx.x;
    int w = tid >> 6, l = tid & 63;
    int lo = l & 15, hi = l >> 4;
    int m0 = blockIdx.x * 64;
    f32x4 acc[4][4];
#pragma unroll
    for (int a = 0; a < 4; ++a)
#pragma unroll
        for (int b = 0; b < 4; ++b) acc[a][b] = (f32x4){0.f, 0.f, 0.f, 0.f};

    for (int bk = 0; bk < 256; bk += 64) {
        __syncthreads();
        // stage A
        if (AFP32) {
#pragma unroll
            for (int i = 0; i < 2; ++i) {
                int c = tid + 256 * i;
                int row = c >> 3, ko = c & 7;
                int rg = m0 + row;
                uint4 v = {0u, 0u, 0u, 0u};
                if (rg < M) {
                    const float* Af = (const float*)Ap;
                    float4 f0 = *(const float4*)(Af + (size_t)rg * 256 + bk + ko * 8);
                    float4 f1 = *(const float4*)(Af + (size_t)rg * 256 + bk + ko * 8 + 4);
                    v.x = (uint)f2bu(f0.x) | ((uint)f2bu(f0.y) << 16);
                    v.y = (uint)f2bu(f0.z) | ((uint)f2bu(f0.w) << 16);
                    v.z = (uint)f2bu(f1.x) | ((uint)f2bu(f1.y) << 16);
                    v.w = (uint)f2bu(f1.z) | ((uint)f2bu(f1.w) << 16);
                }
                *(uint4*)(As + row * 128 + ((ko * 16) ^ ((row & 7) << 4))) = v;
            }
        } else {
#pragma unroll
            for (int i = 0; i < 2; ++i) {
                int c = tid + 256 * i;
                int row = c >> 3, ko = c & 7;   // LDS dest linear: c*16
                gload_lds16((const char*)Ap + (size_t)(m0 + row) * 512 + bk * 2 +
                                ((ko * 16) ^ ((row & 7) << 4)),
                            As + (i * 256 + w * 64) * 16);
            }
        }
        // stage B (always gload_lds)
#pragma unroll
        for (int i = 0; i < 8; ++i) {
            int c = tid + 256 * i;
            int row = c >> 3, ko = c & 7;       // LDS dest linear: c*16
            gload_lds16((const char*)Wt + (size_t)row * 512 + bk * 2 +
                            ((ko * 16) ^ ((row & 7) << 4)),
                        Bs + (i * 256 + w * 64) * 16);
        }
        __syncthreads();
#pragma unroll
        for (int kk = 0; kk < 2; ++kk) {
            int koff = kk * 64 + hi * 16;
            short8 af[4], bfr[4];
#pragma unroll
            for (int mi = 0; mi < 4; ++mi) {
                int row = mi * 16 + lo;
                af[mi] = *(const short8*)(As + row * 128 + (koff ^ ((row & 7) << 4)));
            }
#pragma unroll
            for (int ni = 0; ni < 4; ++ni) {
                int row = w * 64 + ni * 16 + lo;
                bfr[ni] = *(const short8*)(Bs + row * 128 + (koff ^ ((row & 7) << 4)));
            }
#pragma unroll
            for (int mi = 0; mi < 4; ++mi)
#pragma unroll
                for (int ni = 0; ni < 4; ++ni)
                    acc[mi][ni] = __builtin_amdgcn_mfma_f32_16x16x32_bf16(af[mi], bfr[ni], acc[mi][ni], 0, 0, 0);
        }
    }
    // C write
#pragma unroll
    for (int mi = 0; mi < 4; ++mi) {
#pragma unroll
        for (int r = 0; r < 4; ++r) {
            int rg = m0 + mi * 16 + hi * 4 + r;
            if (rg < M) {
#pragma unroll
                for (int ni = 0; ni < 4; ++ni) {
                    int col = w * 64 + ni * 16 + lo;
                    C[(size_t)rg * 256 + col] = __float2bfloat16(acc[mi][ni][r]);
                }
            }
        }
    }
    // fused e_src/e_dst (head w lives entirely in wave w)
    float avv[4], adv[4];
#pragma unroll
    for (int ni = 0; ni < 4; ++ni) {
        avv[ni] = a_src[w * 64 + ni * 16 + lo];
        adv[ni] = a_dst[w * 64 + ni * 16 + lo];
    }
#pragma unroll
    for (int mi = 0; mi < 4; ++mi) {
#pragma unroll
        for (int r = 0; r < 4; ++r) {
            int rg = m0 + mi * 16 + hi * 4 + r;
            float s1 = 0.f, s2 = 0.f;
#pragma unroll
            for (int ni = 0; ni < 4; ++ni) {
                s1 += acc[mi][ni][r] * avv[ni];
                s2 += acc[mi][ni][r] * adv[ni];
            }
#pragma unroll
            for (int mk = 1; mk < 16; mk <<= 1) {
                s1 += __shfl_xor(s1, mk, 64);
                s2 += __shfl_xor(s2, mk, 64);
            }
            if (lo == 0 && rg < M) {
                es[rg * 4 + w] = s1;
                ed[rg * 4 + w] = s2;
            }
        }
    }
}

// ---------------- softmax + aggregate ----------------
// One WAVE per dst node; lane l owns channels [4l..4l+3] (head = l>>4).
// Register-only masked 8-deep unroll (measured local roofline: ~56us at
// ~4 TB/s random-512B L2-fill; FETCH ~167MB is compulsory per-XCD traffic).
// No max subtraction: e = leaky_relu(es+ed) is O(+-10); fp32 exp safe.
// mode 0: out = bf16(relu(acc+b) + x);  1: bf16(relu(acc+b));  2: fp32 relu(acc+b+x)

__global__ __launch_bounds__(256) void k_aggregate(const __hip_bfloat16* __restrict__ hW,
                            const int* __restrict__ rowptr,
                            const int* __restrict__ colsrc, const float* __restrict__ es,
                            const float* __restrict__ edv_, const float* __restrict__ bias,
                            const float* __restrict__ xres, __hip_bfloat16* __restrict__ outbf,
                            float* __restrict__ outf, int mode, int Nn) {
    int n = blockIdx.x * 4 + (threadIdx.x >> 6);
    if (n >= Nn) return;
    int l = threadIdx.x & 63;
    int h = l >> 4;
    int r0 = rowptr[n];
    int deg = rowptr[n + 1] - r0;
    float edv = edv_[n * 4 + h];

    float denom = 0.f;
    float a0 = 0.f, a1 = 0.f, a2 = 0.f, a3 = 0.f;
    const ushort* hw = (const ushort*)hW;
    int sfb = colsrc[r0];  // fallback row for masked lanes (self-loop => deg>=1)

    for (int base = 0; base < deg; base += 8) {
        int sv[8];
#pragma unroll
        for (int u = 0; u < 8; ++u)
            sv[u] = (base + u < deg) ? colsrc[r0 + base + u] : sfb;
        float ev[8];
#pragma unroll
        for (int u = 0; u < 8; ++u)
            ev[u] = es[(size_t)sv[u] * 4 + h];
        uint2 hv[8];
#pragma unroll
        for (int u = 0; u < 8; ++u)
            hv[u] = *(const uint2*)(hw + (size_t)sv[u] * 256 + l * 4);
#pragma unroll
        for (int u = 0; u < 8; ++u) {
            float t = ev[u] + edv;
            t = fmaxf(t, 0.2f * t);
            float p = (base + u < deg) ? __expf(t) : 0.f;
            denom += p;
            a0 += p * bfu((ushort)(hv[u].x & 0xffff));
            a1 += p * bfu((ushort)(hv[u].x >> 16));
            a2 += p * bfu((ushort)(hv[u].y & 0xffff));
            a3 += p * bfu((ushort)(hv[u].y >> 16));
        }
    }

    float inv = 1.f / (denom + 1e-16f);
    int idx = n * 256 + l * 4;
    float4 b4 = *(const float4*)(bias + l * 4);
    float v0 = a0 * inv + b4.x;
    float v1 = a1 * inv + b4.y;
    float v2 = a2 * inv + b4.z;
    float v3 = a3 * inv + b4.w;

    if (mode == 2) {
        float4 x4 = *(const float4*)(xres + idx);
        float4 o;
        o.x = fmaxf(v0 + x4.x, 0.f);
        o.y = fmaxf(v1 + x4.y, 0.f);
        o.z = fmaxf(v2 + x4.z, 0.f);
        o.w = fmaxf(v3 + x4.w, 0.f);
        *(float4*)(outf + idx) = o;
    } else {
        v0 = fmaxf(v0, 0.f); v1 = fmaxf(v1, 0.f);
        v2 = fmaxf(v2, 0.f); v3 = fmaxf(v3, 0.f);
        if (mode == 0) {
            float4 x4 = *(const float4*)(xres + idx);
            v0 += x4.x; v1 += x4.y; v2 += x4.z; v3 += x4.w;
        }
        union { ushort u[4]; uint2 v; } o;
        o.u[0] = f2bu(v0); o.u[1] = f2bu(v1);
        o.u[2] = f2bu(v2); o.u[3] = f2bu(v3);
        *(uint2*)((ushort*)outbf + idx) = o.v;
    }
}

// ---------------- launch ----------------

extern "C" void kernel_launch(void* const* d_in, const int* in_sizes, int n_in,
                              void* d_out, int out_size, void* d_ws, size_t ws_size,
                              hipStream_t stream) {
    const float* x  = (const float*)d_in[0];
    const int* ei   = (const int*)d_in[1];
    const float* W1 = (const float*)d_in[2];
    const float* as1 = (const float*)d_in[3];
    const float* ad1 = (const float*)d_in[4];
    const float* b1  = (const float*)d_in[5];
    const float* W2  = (const float*)d_in[6];
    const float* as2 = (const float*)d_in[7];
    const float* ad2 = (const float*)d_in[8];
    const float* b2  = (const float*)d_in[9];
    const float* WN  = (const float*)d_in[10];
    const float* asN = (const float*)d_in[11];
    const float* adN = (const float*)d_in[12];
    const float* bN  = (const float*)d_in[13];

    int Nn = in_sizes[0] / 256;
    int E = in_sizes[1] / 2;
    const int* srcv = ei;
    const int* dstv = ei + E;
    int Etot = E + Nn;

    char* p = (char*)d_ws;
    auto alloc = [&](size_t bytes) {
        char* r = p;
        p += (bytes + 255) & ~(size_t)255;
        return r;
    };
    // +32KB pad: gload_lds staging of the ragged last tile reads past row M
    __hip_bfloat16* Pbf  = (__hip_bfloat16*)alloc((size_t)Nn * 256 * 2 + 32768);
    __hip_bfloat16* Qbf  = (__hip_bfloat16*)alloc((size_t)Nn * 256 * 2 + 32768);
    __hip_bfloat16* hWbf = (__hip_bfloat16*)alloc((size_t)Nn * 256 * 2);
    __hip_bfloat16* Wt1  = (__hip_bfloat16*)alloc(256 * 256 * 2);
    __hip_bfloat16* Wt2  = (__hip_bfloat16*)alloc(256 * 256 * 2);
    __hip_bfloat16* Wt3  = (__hip_bfloat16*)alloc(256 * 256 * 2);
    float* esrc = (float*)alloc((size_t)Nn * 4 * 4);
    float* edst = (float*)alloc((size_t)Nn * 4 * 4);
    int* cnt    = (int*)alloc((size_t)Nn * 4);
    int* excl   = (int*)alloc((size_t)Nn * 4);
    int* rowptr = (int*)alloc((size_t)(Nn + 1) * 4);
    int* cursor = (int*)alloc((size_t)Nn * 4);
    int* bsum   = (int*)alloc(4096);
    int* boff   = (int*)alloc(4096);
    int* colsrc = (int*)alloc((size_t)Etot * 4);

    int nb = (Nn + 255) / 256;

    // prep: weight transpose+cast (coalesced, one launch)
    dim3 wg(4, 4, 3);
    k_wt_cast3<<<wg, 256, 0, stream>>>(W1, W2, WN, Wt1, Wt2, Wt3);

    // CSR build (dst-sorted, with self-loops folded into hist/scatter)
    hipMemsetAsync(cnt, 0, (size_t)Nn * 4, stream);
    k_hist<<<(Etot + 255) / 256, 256, 0, stream>>>(dstv, cnt, E, Nn);
    k_scan1<<<nb, 256, 0, stream>>>(cnt, excl, bsum, Nn);
    k_scan2<<<1, 256, 0, stream>>>(bsum, boff, nb);
    k_scan3<<<nb, 256, 0, stream>>>(excl, boff, rowptr, cursor, Nn, Etot);
    k_scatter<<<(Etot + 255) / 256, 256, 0, stream>>>(srcv, dstv, cursor, colsrc, E, Nn);

    int gg = (Nn + 63) / 64;
    int ga = (Nn + 3) / 4;

    // layer 1 (fp32 x staged directly)
    k_gemm<true><<<gg, 256, 0, stream>>>(x, Wt1, hWbf, as1, ad1, esrc, edst, Nn);
    k_aggregate<<<ga, 256, 0, stream>>>(hWbf, rowptr, colsrc, esrc, edst, b1, x, Pbf, nullptr, 0, Nn);
    // layer 2
    k_gemm<false><<<gg, 256, 0, stream>>>(Pbf, Wt2, hWbf, as2, ad2, esrc, edst, Nn);
    k_aggregate<<<ga, 256, 0, stream>>>(hWbf, rowptr, colsrc, esrc, edst, b2, x, Qbf, nullptr, 1, Nn);
    // layer 3
    k_gemm<false><<<gg, 256, 0, stream>>>(Qbf, Wt3, hWbf, asN, adN, esrc, edst, Nn);
    k_aggregate<<<ga, 256, 0, stream>>>(hWbf, rowptr, colsrc, esrc, edst, bN, x, nullptr, (float*)d_out, 2, Nn);
}